// Round 1
// baseline (59.339 us; speedup 1.0000x reference)
//
#include <hip/hip_runtime.h>
#include <math.h>

// GeometricController: 55 floats in -> 4 floats out. Pure scalar control law.
// Single block / single active lane; latency-bound (launch overhead dominates).

namespace {

struct V3 { float x, y, z; };
struct M3 { float a[3][3]; };

__device__ __forceinline__ V3 v3(float x, float y, float z) { return V3{x, y, z}; }
__device__ __forceinline__ V3 operator+(V3 a, V3 b) { return V3{a.x + b.x, a.y + b.y, a.z + b.z}; }
__device__ __forceinline__ V3 operator-(V3 a, V3 b) { return V3{a.x - b.x, a.y - b.y, a.z - b.z}; }
__device__ __forceinline__ V3 operator*(float s, V3 a) { return V3{s * a.x, s * a.y, s * a.z}; }
__device__ __forceinline__ float dot(V3 a, V3 b) { return a.x * b.x + a.y * b.y + a.z * b.z; }
__device__ __forceinline__ V3 cross(V3 a, V3 b) {
    return V3{a.y * b.z - a.z * b.y,
              a.z * b.x - a.x * b.z,
              a.x * b.y - a.y * b.x};
}
__device__ __forceinline__ V3 normalize(V3 a) {
    float n = sqrtf(dot(a, a));
    return (1.0f / n) * a;
}
__device__ __forceinline__ V3 matvec(const M3& m, V3 v) {
    return V3{m.a[0][0] * v.x + m.a[0][1] * v.y + m.a[0][2] * v.z,
              m.a[1][0] * v.x + m.a[1][1] * v.y + m.a[1][2] * v.z,
              m.a[2][0] * v.x + m.a[2][1] * v.y + m.a[2][2] * v.z};
}
__device__ __forceinline__ V3 matTvec(const M3& m, V3 v) {
    return V3{m.a[0][0] * v.x + m.a[1][0] * v.y + m.a[2][0] * v.z,
              m.a[0][1] * v.x + m.a[1][1] * v.y + m.a[2][1] * v.z,
              m.a[0][2] * v.x + m.a[1][2] * v.y + m.a[2][2] * v.z};
}
// C = A^T * B
__device__ __forceinline__ M3 mtm(const M3& A, const M3& B) {
    M3 C;
    for (int i = 0; i < 3; ++i)
        for (int j = 0; j < 3; ++j)
            C.a[i][j] = A.a[0][i] * B.a[0][j] + A.a[1][i] * B.a[1][j] + A.a[2][i] * B.a[2][j];
    return C;
}
// C = A * B
__device__ __forceinline__ M3 mm(const M3& A, const M3& B) {
    M3 C;
    for (int i = 0; i < 3; ++i)
        for (int j = 0; j < 3; ++j)
            C.a[i][j] = A.a[i][0] * B.a[0][j] + A.a[i][1] * B.a[1][j] + A.a[i][2] * B.a[2][j];
    return C;
}
__device__ __forceinline__ M3 msub(const M3& A, const M3& B) {
    M3 C;
    for (int i = 0; i < 3; ++i)
        for (int j = 0; j < 3; ++j)
            C.a[i][j] = A.a[i][j] - B.a[i][j];
    return C;
}
__device__ __forceinline__ M3 mscale(float s, const M3& A) {
    M3 C;
    for (int i = 0; i < 3; ++i)
        for (int j = 0; j < 3; ++j)
            C.a[i][j] = s * A.a[i][j];
    return C;
}
__device__ __forceinline__ M3 skew(V3 v) {
    M3 m;
    m.a[0][0] = 0.0f;  m.a[0][1] = -v.z; m.a[0][2] = v.y;
    m.a[1][0] = v.z;   m.a[1][1] = 0.0f; m.a[1][2] = -v.x;
    m.a[2][0] = -v.y;  m.a[2][1] = v.x;  m.a[2][2] = 0.0f;
    return m;
}
__device__ __forceinline__ V3 skew2vec(const M3& m) {
    return V3{-m.a[1][2], m.a[0][2], -m.a[0][1]};
}

} // namespace

__global__ void GeometricController_kernel(const float* __restrict__ state,
                                           const float* __restrict__ ref_state,
                                           const float* __restrict__ Jp,
                                           float* __restrict__ out) {
    if (threadIdx.x != 0 || blockIdx.x != 0) return;

    const float m = 4.34f, g = 9.81f;
    const float kp = 16.0f, kv = 5.6f, kori = 8.81f, kw = 2.54f;

    // --- unpack state ---
    V3 pos = v3(state[0], state[1], state[2]);
    float qx = state[3], qy = state[4], qz = state[5], qw = state[6];  // pypose (x,y,z,w)
    V3 vel = v3(state[7], state[8], state[9]);
    V3 w   = v3(state[10], state[11], state[12]);

    M3 R;
    R.a[0][0] = 1.0f - 2.0f * (qy * qy + qz * qz);
    R.a[0][1] = 2.0f * (qx * qy - qz * qw);
    R.a[0][2] = 2.0f * (qx * qz + qy * qw);
    R.a[1][0] = 2.0f * (qx * qy + qz * qw);
    R.a[1][1] = 1.0f - 2.0f * (qx * qx + qz * qz);
    R.a[1][2] = 2.0f * (qy * qz - qx * qw);
    R.a[2][0] = 2.0f * (qx * qz - qy * qw);
    R.a[2][1] = 2.0f * (qy * qz + qx * qw);
    R.a[2][2] = 1.0f - 2.0f * (qx * qx + qy * qy);

    M3 J;
    for (int i = 0; i < 3; ++i)
        for (int j = 0; j < 3; ++j)
            J.a[i][j] = Jp[3 * i + j];

    // --- unpack ref_state ---
    V3 rr[11];
    for (int i = 0; i < 11; ++i)
        rr[i] = v3(ref_state[3 * i], ref_state[3 * i + 1], ref_state[3 * i + 2]);
    V3 des_pos = rr[0], des_vel = rr[1];
    V3 des_acc = rr[2], des_acc_d = rr[3], des_acc_dd = rr[4], des_acc_ddd = rr[5], des_acc_dddd = rr[6];
    V3 des_b1 = rr[7], des_b1_d = rr[8], des_b1_dd = rr[9], des_b1_ddd = rr[10];

    const V3 e3 = v3(0.0f, 0.0f, 1.0f);

    // body z axis & its derivatives in world frame
    V3 b3 = v3(R.a[0][2], R.a[1][2], R.a[2][2]);  // R @ e3
    V3 u1 = cross(w, e3);                          // wx @ e3
    V3 u2 = cross(w, u1);                          // wx @ wx @ e3
    V3 u3 = cross(w, u2);                          // wx^3 @ e3
    V3 b3_d   = matvec(R, u1);
    V3 b3_dd  = matvec(R, u2);
    V3 b3_ddd = matvec(R, u3);

    // desired b3 chain (thrust derivatives)
    V3 des_b3 = (-kp) * (pos - des_pos) + (-kv) * (vel - des_vel) + v3(0.0f, 0.0f, -m * g) + m * des_acc;
    float thrust = -dot(des_b3, b3);

    V3 ev_d = v3(0.0f, 0.0f, g) + (-thrust / m) * b3 + (-1.0f) * des_acc;
    V3 des_b3_d = (-kp) * (vel - des_vel) + (-kv) * ev_d + m * des_acc_d;
    float thrust_d = -dot(des_b3_d, b3) - dot(des_b3, b3_d);

    V3 ev_dd = (1.0f / m) * ((-thrust_d) * b3 + (-thrust) * b3_d) + (-1.0f) * des_acc_d;
    V3 des_b3_dd = (-kp) * ev_d + (-kv) * ev_dd + m * des_acc_dd;
    float thrust_dd = -dot(des_b3_dd, b3) - 2.0f * dot(des_b3_d, b3_d) - dot(des_b3, b3_dd);

    V3 ev_ddd = (1.0f / m) * ((-thrust_dd) * b3 + (-2.0f * thrust_d) * b3_d + (-thrust) * b3_dd)
                + (-1.0f) * des_acc_ddd;
    V3 des_b3_ddd = (-kp) * ev_dd + (-kv) * ev_ddd + m * des_acc_ddd;
    float thrust_ddd = -dot(des_b3_ddd, b3) - 3.0f * dot(des_b3_dd, b3_d)
                       - 3.0f * dot(des_b3_d, b3_dd) - dot(des_b3, b3_ddd);

    V3 ev_dddd = (1.0f / m) * ((-thrust_ddd) * b3 + (-3.0f * thrust_dd) * b3_d
                               + (-3.0f * thrust_d) * b3_dd + (-thrust) * b3_ddd)
                 + (-1.0f) * des_acc_dddd;
    V3 des_b3_dddd = (-kp) * ev_ddd + (-kv) * ev_dddd + m * des_acc_dddd;

    // negate + independently normalize each (exactly what the reference does)
    des_b3      = normalize((-1.0f) * des_b3);
    des_b3_d    = normalize((-1.0f) * des_b3_d);
    des_b3_dd   = normalize((-1.0f) * des_b3_dd);
    des_b3_ddd  = normalize((-1.0f) * des_b3_ddd);
    des_b3_dddd = normalize((-1.0f) * des_b3_dddd);

    // b2 chain (Leibniz; note dddd has only 4 terms — no des_b1_dddd available)
    V3 b2      = cross(des_b3, des_b1);
    V3 b2_d    = cross(des_b3_d, des_b1) + cross(des_b3, des_b1_d);
    V3 b2_dd   = cross(des_b3_dd, des_b1) + 2.0f * cross(des_b3_d, des_b1_d) + cross(des_b3, des_b1_dd);
    V3 b2_ddd  = cross(des_b3_ddd, des_b1) + 3.0f * cross(des_b3_dd, des_b1_d)
               + 3.0f * cross(des_b3_d, des_b1_dd) + cross(des_b3, des_b1_ddd);
    V3 b2_dddd = cross(des_b3_dddd, des_b1) + 4.0f * cross(des_b3_ddd, des_b1_d)
               + 6.0f * cross(des_b3_dd, des_b1_dd) + 4.0f * cross(des_b3_d, des_b1_ddd);

    b2      = normalize(b2);
    b2_d    = normalize(b2_d);
    b2_dd   = normalize(b2_dd);
    b2_ddd  = normalize(b2_ddd);
    b2_dddd = normalize(b2_dddd);

    // b1 chain (full 5-term Leibniz at dddd)
    V3 b1      = cross(b2, des_b3);
    V3 b1_d    = cross(b2_d, des_b3) + cross(b2, des_b3_d);
    V3 b1_dd   = cross(b2_dd, des_b3) + 2.0f * cross(b2_d, des_b3_d) + cross(b2, des_b3_dd);
    V3 b1_ddd  = cross(b2_ddd, des_b3) + 3.0f * cross(b2_dd, des_b3_d)
               + 3.0f * cross(b2_d, des_b3_dd) + cross(b2, des_b3_ddd);
    V3 b1_dddd = cross(b2_dddd, des_b3) + 4.0f * cross(b2_ddd, des_b3_d)
               + 6.0f * cross(b2_dd, des_b3_dd) + 4.0f * cross(b2_d, des_b3_ddd)
               + cross(b2, des_b3_dddd);

    b1      = normalize(b1);
    b1_d    = normalize(b1_d);
    b1_dd   = normalize(b1_dd);
    b1_ddd  = normalize(b1_ddd);
    b1_dddd = normalize(b1_dddd);

    // Rd and its derivatives: columns [b1, b2, des_b3]
    auto make_cols = [](V3 c0, V3 c1, V3 c2) {
        M3 r;
        r.a[0][0] = c0.x; r.a[1][0] = c0.y; r.a[2][0] = c0.z;
        r.a[0][1] = c1.x; r.a[1][1] = c1.y; r.a[2][1] = c1.z;
        r.a[0][2] = c2.x; r.a[1][2] = c2.y; r.a[2][2] = c2.z;
        return r;
    };
    M3 Rd      = make_cols(b1, b2, des_b3);
    M3 Rd_d    = make_cols(b1_d, b2_d, des_b3_d);
    M3 Rd_dd   = make_cols(b1_dd, b2_dd, des_b3_dd);
    M3 Rd_ddd  = make_cols(b1_ddd, b2_ddd, des_b3_ddd);
    M3 Rd_dddd = make_cols(b1_dddd, b2_dddd, des_b3_dddd);

    // angular references
    V3 w_d = skew2vec(mtm(Rd, Rd_d));
    M3 W = skew(w_d);
    M3 WW = mm(W, W);
    V3 a_d = skew2vec(msub(mtm(Rd, Rd_dd), WW));
    M3 Aa = skew(a_d);
    V3 j_d = skew2vec(msub(mtm(Rd, Rd_ddd), mscale(3.0f, mm(W, Aa))));
    M3 Aj = skew(j_d);
    V3 s_d = skew2vec(msub(msub(mtm(Rd, Rd_dddd), mscale(4.0f, mm(W, Aj))),
                           mscale(3.0f, mm(Aa, Aa))));

    // attitude errors
    M3 B = mtm(Rd, R);  // Rd^T R ; R^T Rd = B^T
    V3 e_R = 0.5f * v3(-(B.a[1][2] - B.a[2][1]),
                       (B.a[0][2] - B.a[2][0]),
                       -(B.a[0][1] - B.a[1][0]));
    V3 e_w = w - matTvec(R, matvec(Rd, w_d));

    // moments
    V3 M = (-1.0f) * (kori * e_R + kw * e_w) + cross(w, matvec(J, w));
    V3 temp = w_d - a_d - j_d - s_d;
    V3 temp_M = cross(w, matTvec(R, matvec(Rd, temp)));  // wx @ (R^T @ (Rd @ temp))
    M = M - matvec(J, temp_M);

    out[0] = fmaxf(0.0f, thrust);
    out[1] = M.x;
    out[2] = M.y;
    out[3] = M.z;
}

extern "C" void kernel_launch(void* const* d_in, const int* in_sizes, int n_in,
                              void* d_out, int out_size, void* d_ws, size_t ws_size,
                              hipStream_t stream) {
    (void)in_sizes; (void)n_in; (void)out_size; (void)d_ws; (void)ws_size;
    const float* state     = (const float*)d_in[0];
    const float* ref_state = (const float*)d_in[1];
    const float* J         = (const float*)d_in[2];
    float* out = (float*)d_out;
    GeometricController_kernel<<<1, 64, 0, stream>>>(state, ref_state, J, out);
}

// Round 2
// 57.945 us; speedup vs baseline: 1.0241x; 1.0241x over previous
//
#include <hip/hip_runtime.h>
#include <math.h>

// GeometricController: 55 floats in -> 4 floats out. Pure scalar control law.
// Single block / single active lane; latency-bound (launch overhead dominates).
// R1: rsqrt-based normalize, reciprocal-mul for /m, batched float4 input loads.

namespace {

struct V3 { float x, y, z; };
struct M3 { float a[3][3]; };

__device__ __forceinline__ V3 v3(float x, float y, float z) { return V3{x, y, z}; }
__device__ __forceinline__ V3 operator+(V3 a, V3 b) { return V3{a.x + b.x, a.y + b.y, a.z + b.z}; }
__device__ __forceinline__ V3 operator-(V3 a, V3 b) { return V3{a.x - b.x, a.y - b.y, a.z - b.z}; }
__device__ __forceinline__ V3 operator*(float s, V3 a) { return V3{s * a.x, s * a.y, s * a.z}; }
__device__ __forceinline__ float dot(V3 a, V3 b) { return a.x * b.x + a.y * b.y + a.z * b.z; }
__device__ __forceinline__ V3 cross(V3 a, V3 b) {
    return V3{a.y * b.z - a.z * b.y,
              a.z * b.x - a.x * b.z,
              a.x * b.y - a.y * b.x};
}
// normalize via v_rsq_f32: one transcendental + 3 muls on the critical path
// (vs sqrt + IEEE div-fixup sequence). Rel err ~1e-6 << 7.3e-2 threshold.
__device__ __forceinline__ V3 normalize(V3 a) {
    float r = rsqrtf(dot(a, a));
    return r * a;
}
__device__ __forceinline__ V3 matvec(const M3& m, V3 v) {
    return V3{m.a[0][0] * v.x + m.a[0][1] * v.y + m.a[0][2] * v.z,
              m.a[1][0] * v.x + m.a[1][1] * v.y + m.a[1][2] * v.z,
              m.a[2][0] * v.x + m.a[2][1] * v.y + m.a[2][2] * v.z};
}
__device__ __forceinline__ V3 matTvec(const M3& m, V3 v) {
    return V3{m.a[0][0] * v.x + m.a[1][0] * v.y + m.a[2][0] * v.z,
              m.a[0][1] * v.x + m.a[1][1] * v.y + m.a[2][1] * v.z,
              m.a[0][2] * v.x + m.a[1][2] * v.y + m.a[2][2] * v.z};
}
// C = A^T * B
__device__ __forceinline__ M3 mtm(const M3& A, const M3& B) {
    M3 C;
    for (int i = 0; i < 3; ++i)
        for (int j = 0; j < 3; ++j)
            C.a[i][j] = A.a[0][i] * B.a[0][j] + A.a[1][i] * B.a[1][j] + A.a[2][i] * B.a[2][j];
    return C;
}
// C = A * B
__device__ __forceinline__ M3 mm(const M3& A, const M3& B) {
    M3 C;
    for (int i = 0; i < 3; ++i)
        for (int j = 0; j < 3; ++j)
            C.a[i][j] = A.a[i][0] * B.a[0][j] + A.a[i][1] * B.a[1][j] + A.a[i][2] * B.a[2][j];
    return C;
}
__device__ __forceinline__ M3 msub(const M3& A, const M3& B) {
    M3 C;
    for (int i = 0; i < 3; ++i)
        for (int j = 0; j < 3; ++j)
            C.a[i][j] = A.a[i][j] - B.a[i][j];
    return C;
}
__device__ __forceinline__ M3 mscale(float s, const M3& A) {
    M3 C;
    for (int i = 0; i < 3; ++i)
        for (int j = 0; j < 3; ++j)
            C.a[i][j] = s * A.a[i][j];
    return C;
}
__device__ __forceinline__ M3 skew(V3 v) {
    M3 m;
    m.a[0][0] = 0.0f;  m.a[0][1] = -v.z; m.a[0][2] = v.y;
    m.a[1][0] = v.z;   m.a[1][1] = 0.0f; m.a[1][2] = -v.x;
    m.a[2][0] = -v.y;  m.a[2][1] = v.x;  m.a[2][2] = 0.0f;
    return m;
}
__device__ __forceinline__ V3 skew2vec(const M3& m) {
    return V3{-m.a[1][2], m.a[0][2], -m.a[0][1]};
}

} // namespace

__global__ void GeometricController_kernel(const float4* __restrict__ state4,
                                           const float* __restrict__ state_tail,
                                           const float4* __restrict__ ref4,
                                           const float* __restrict__ ref_tail,
                                           const float4* __restrict__ J4,
                                           const float* __restrict__ J_tail,
                                           float* __restrict__ out) {
    if (threadIdx.x != 0 || blockIdx.x != 0) return;

    const float m = 4.34f, g = 9.81f;
    const float inv_m = 1.0f / 4.34f;
    const float kp = 16.0f, kv = 5.6f, kori = 8.81f, kw = 2.54f;

    // --- batch ALL global loads up front (overlap HBM-miss latency) ---
    float4 s0 = state4[0], s1 = state4[1], s2 = state4[2];
    float s12 = state_tail[12];
    float4 r0 = ref4[0], r1 = ref4[1], r2 = ref4[2], r3 = ref4[3],
           r4 = ref4[4], r5 = ref4[5], r6 = ref4[6], r7 = ref4[7];
    float r32 = ref_tail[32];
    float4 j0 = J4[0], j1 = J4[1];
    float j8 = J_tail[8];

    float sf[13] = {s0.x, s0.y, s0.z, s0.w, s1.x, s1.y, s1.z, s1.w,
                    s2.x, s2.y, s2.z, s2.w, s12};
    float rf[33] = {r0.x, r0.y, r0.z, r0.w, r1.x, r1.y, r1.z, r1.w,
                    r2.x, r2.y, r2.z, r2.w, r3.x, r3.y, r3.z, r3.w,
                    r4.x, r4.y, r4.z, r4.w, r5.x, r5.y, r5.z, r5.w,
                    r6.x, r6.y, r6.z, r6.w, r7.x, r7.y, r7.z, r7.w, r32};

    // --- unpack state ---
    V3 pos = v3(sf[0], sf[1], sf[2]);
    float qx = sf[3], qy = sf[4], qz = sf[5], qw = sf[6];  // pypose (x,y,z,w)
    V3 vel = v3(sf[7], sf[8], sf[9]);
    V3 w   = v3(sf[10], sf[11], sf[12]);

    M3 R;
    R.a[0][0] = 1.0f - 2.0f * (qy * qy + qz * qz);
    R.a[0][1] = 2.0f * (qx * qy - qz * qw);
    R.a[0][2] = 2.0f * (qx * qz + qy * qw);
    R.a[1][0] = 2.0f * (qx * qy + qz * qw);
    R.a[1][1] = 1.0f - 2.0f * (qx * qx + qz * qz);
    R.a[1][2] = 2.0f * (qy * qz - qx * qw);
    R.a[2][0] = 2.0f * (qx * qz - qy * qw);
    R.a[2][1] = 2.0f * (qy * qz + qx * qw);
    R.a[2][2] = 1.0f - 2.0f * (qx * qx + qy * qy);

    M3 J;
    J.a[0][0] = j0.x; J.a[0][1] = j0.y; J.a[0][2] = j0.z;
    J.a[1][0] = j0.w; J.a[1][1] = j1.x; J.a[1][2] = j1.y;
    J.a[2][0] = j1.z; J.a[2][1] = j1.w; J.a[2][2] = j8;

    // --- unpack ref_state ---
    V3 des_pos = v3(rf[0], rf[1], rf[2]),   des_vel = v3(rf[3], rf[4], rf[5]);
    V3 des_acc = v3(rf[6], rf[7], rf[8]),   des_acc_d = v3(rf[9], rf[10], rf[11]);
    V3 des_acc_dd = v3(rf[12], rf[13], rf[14]), des_acc_ddd = v3(rf[15], rf[16], rf[17]);
    V3 des_acc_dddd = v3(rf[18], rf[19], rf[20]);
    V3 des_b1 = v3(rf[21], rf[22], rf[23]), des_b1_d = v3(rf[24], rf[25], rf[26]);
    V3 des_b1_dd = v3(rf[27], rf[28], rf[29]), des_b1_ddd = v3(rf[30], rf[31], rf[32]);

    const V3 e3 = v3(0.0f, 0.0f, 1.0f);

    // body z axis & its derivatives in world frame
    V3 b3 = v3(R.a[0][2], R.a[1][2], R.a[2][2]);  // R @ e3
    V3 u1 = cross(w, e3);                          // wx @ e3
    V3 u2 = cross(w, u1);                          // wx @ wx @ e3
    V3 u3 = cross(w, u2);                          // wx^3 @ e3
    V3 b3_d   = matvec(R, u1);
    V3 b3_dd  = matvec(R, u2);
    V3 b3_ddd = matvec(R, u3);

    // desired b3 chain (thrust derivatives)
    V3 des_b3 = (-kp) * (pos - des_pos) + (-kv) * (vel - des_vel) + v3(0.0f, 0.0f, -m * g) + m * des_acc;
    float thrust = -dot(des_b3, b3);

    V3 ev_d = v3(0.0f, 0.0f, g) + (-thrust * inv_m) * b3 + (-1.0f) * des_acc;
    V3 des_b3_d = (-kp) * (vel - des_vel) + (-kv) * ev_d + m * des_acc_d;
    float thrust_d = -dot(des_b3_d, b3) - dot(des_b3, b3_d);

    V3 ev_dd = inv_m * ((-thrust_d) * b3 + (-thrust) * b3_d) + (-1.0f) * des_acc_d;
    V3 des_b3_dd = (-kp) * ev_d + (-kv) * ev_dd + m * des_acc_dd;
    float thrust_dd = -dot(des_b3_dd, b3) - 2.0f * dot(des_b3_d, b3_d) - dot(des_b3, b3_dd);

    V3 ev_ddd = inv_m * ((-thrust_dd) * b3 + (-2.0f * thrust_d) * b3_d + (-thrust) * b3_dd)
                + (-1.0f) * des_acc_ddd;
    V3 des_b3_ddd = (-kp) * ev_dd + (-kv) * ev_ddd + m * des_acc_ddd;
    float thrust_ddd = -dot(des_b3_ddd, b3) - 3.0f * dot(des_b3_dd, b3_d)
                       - 3.0f * dot(des_b3_d, b3_dd) - dot(des_b3, b3_ddd);

    V3 ev_dddd = inv_m * ((-thrust_ddd) * b3 + (-3.0f * thrust_dd) * b3_d
                          + (-3.0f * thrust_d) * b3_dd + (-thrust) * b3_ddd)
                 + (-1.0f) * des_acc_dddd;
    V3 des_b3_dddd = (-kp) * ev_ddd + (-kv) * ev_dddd + m * des_acc_dddd;

    // negate + independently normalize each (exactly what the reference does)
    des_b3      = normalize((-1.0f) * des_b3);
    des_b3_d    = normalize((-1.0f) * des_b3_d);
    des_b3_dd   = normalize((-1.0f) * des_b3_dd);
    des_b3_ddd  = normalize((-1.0f) * des_b3_ddd);
    des_b3_dddd = normalize((-1.0f) * des_b3_dddd);

    // b2 chain (Leibniz; dddd has only 4 terms — no des_b1_dddd available)
    V3 b2      = cross(des_b3, des_b1);
    V3 b2_d    = cross(des_b3_d, des_b1) + cross(des_b3, des_b1_d);
    V3 b2_dd   = cross(des_b3_dd, des_b1) + 2.0f * cross(des_b3_d, des_b1_d) + cross(des_b3, des_b1_dd);
    V3 b2_ddd  = cross(des_b3_ddd, des_b1) + 3.0f * cross(des_b3_dd, des_b1_d)
               + 3.0f * cross(des_b3_d, des_b1_dd) + cross(des_b3, des_b1_ddd);
    V3 b2_dddd = cross(des_b3_dddd, des_b1) + 4.0f * cross(des_b3_ddd, des_b1_d)
               + 6.0f * cross(des_b3_dd, des_b1_dd) + 4.0f * cross(des_b3_d, des_b1_ddd);

    b2      = normalize(b2);
    b2_d    = normalize(b2_d);
    b2_dd   = normalize(b2_dd);
    b2_ddd  = normalize(b2_ddd);
    b2_dddd = normalize(b2_dddd);

    // b1 chain (full 5-term Leibniz at dddd)
    V3 b1      = cross(b2, des_b3);
    V3 b1_d    = cross(b2_d, des_b3) + cross(b2, des_b3_d);
    V3 b1_dd   = cross(b2_dd, des_b3) + 2.0f * cross(b2_d, des_b3_d) + cross(b2, des_b3_dd);
    V3 b1_ddd  = cross(b2_ddd, des_b3) + 3.0f * cross(b2_dd, des_b3_d)
               + 3.0f * cross(b2_d, des_b3_dd) + cross(b2, des_b3_ddd);
    V3 b1_dddd = cross(b2_dddd, des_b3) + 4.0f * cross(b2_ddd, des_b3_d)
               + 6.0f * cross(b2_dd, des_b3_dd) + 4.0f * cross(b2_d, des_b3_ddd)
               + cross(b2, des_b3_dddd);

    b1      = normalize(b1);
    b1_d    = normalize(b1_d);
    b1_dd   = normalize(b1_dd);
    b1_ddd  = normalize(b1_ddd);
    b1_dddd = normalize(b1_dddd);

    // Rd and its derivatives: columns [b1, b2, des_b3]
    auto make_cols = [](V3 c0, V3 c1, V3 c2) {
        M3 r;
        r.a[0][0] = c0.x; r.a[1][0] = c0.y; r.a[2][0] = c0.z;
        r.a[0][1] = c1.x; r.a[1][1] = c1.y; r.a[2][1] = c1.z;
        r.a[0][2] = c2.x; r.a[1][2] = c2.y; r.a[2][2] = c2.z;
        return r;
    };
    M3 Rd      = make_cols(b1, b2, des_b3);
    M3 Rd_d    = make_cols(b1_d, b2_d, des_b3_d);
    M3 Rd_dd   = make_cols(b1_dd, b2_dd, des_b3_dd);
    M3 Rd_ddd  = make_cols(b1_ddd, b2_ddd, des_b3_ddd);
    M3 Rd_dddd = make_cols(b1_dddd, b2_dddd, des_b3_dddd);

    // angular references
    V3 w_d = skew2vec(mtm(Rd, Rd_d));
    M3 W = skew(w_d);
    M3 WW = mm(W, W);
    V3 a_d = skew2vec(msub(mtm(Rd, Rd_dd), WW));
    M3 Aa = skew(a_d);
    V3 j_d = skew2vec(msub(mtm(Rd, Rd_ddd), mscale(3.0f, mm(W, Aa))));
    M3 Aj = skew(j_d);
    V3 s_d = skew2vec(msub(msub(mtm(Rd, Rd_dddd), mscale(4.0f, mm(W, Aj))),
                           mscale(3.0f, mm(Aa, Aa))));

    // attitude errors
    M3 B = mtm(Rd, R);  // Rd^T R ; R^T Rd = B^T
    V3 e_R = 0.5f * v3(-(B.a[1][2] - B.a[2][1]),
                       (B.a[0][2] - B.a[2][0]),
                       -(B.a[0][1] - B.a[1][0]));
    V3 e_w = w - matTvec(R, matvec(Rd, w_d));

    // moments
    V3 M = (-1.0f) * (kori * e_R + kw * e_w) + cross(w, matvec(J, w));
    V3 temp = w_d - a_d - j_d - s_d;
    V3 temp_M = cross(w, matTvec(R, matvec(Rd, temp)));  // wx @ (R^T @ (Rd @ temp))
    M = M - matvec(J, temp_M);

    out[0] = fmaxf(0.0f, thrust);
    out[1] = M.x;
    out[2] = M.y;
    out[3] = M.z;
}

extern "C" void kernel_launch(void* const* d_in, const int* in_sizes, int n_in,
                              void* d_out, int out_size, void* d_ws, size_t ws_size,
                              hipStream_t stream) {
    (void)in_sizes; (void)n_in; (void)out_size; (void)d_ws; (void)ws_size;
    const float* state     = (const float*)d_in[0];
    const float* ref_state = (const float*)d_in[1];
    const float* J         = (const float*)d_in[2];
    float* out = (float*)d_out;
    GeometricController_kernel<<<1, 64, 0, stream>>>(
        (const float4*)state, state,
        (const float4*)ref_state, ref_state,
        (const float4*)J, J,
        out);
}